// Round 3
// baseline (132.600 us; speedup 1.0000x reference)
//
#include <hip/hip_runtime.h>

// ThinPlateSpline: out = K_query @ rbf_weights + P_query @ poly_coeffs
//   K_ij = r*ln(r), r = ||u_i - c_j|| (d=3);  r*ln(r) = sqrt(r2)*C*log2(r2),
//   C = 0.5*ln2 folded into pre-scaled weights.
//
// R3: control-point data is wave-uniform -> read it via loop-uniform global
// loads so the compiler emits s_load_dwordx8 (scalar pipe, zero VALU/LDS
// cost). A pre-pack kernel writes {-2c, |c|^2, C*w} per point into d_ws so
// r2 = fma chain (4 full-rate ops) and one 32B-aligned scalar load per j.
// QPT=4 gives 4 independent chains/lane to hide sqrt/log latency.
// grid (16,128) = 2048 blocks -> ~8 waves/SIMD.

#define BLK 256
#define QPT 4
#define CHUNK 32

__global__ void pack_kernel(const float* __restrict__ cp,
                            const float* __restrict__ w,
                            float4* __restrict__ pack, int n) {
    const int j = blockIdx.x * blockDim.x + threadIdx.x;
    if (j >= n) return;
    const float C = 0.34657359027997264f;  // 0.5 * ln(2)
    const float cx = cp[j * 3 + 0], cy = cp[j * 3 + 1], cz = cp[j * 3 + 2];
    pack[j * 2 + 0] = make_float4(-2.f * cx, -2.f * cy, -2.f * cz,
                                  cx * cx + cy * cy + cz * cz);
    pack[j * 2 + 1] = make_float4(C * w[j * 3 + 0], C * w[j * 3 + 1],
                                  C * w[j * 3 + 2], 0.f);
}

__global__ __launch_bounds__(BLK) void tps_kernel(
    const float* __restrict__ u,     // (batch, 3)
    const float* __restrict__ pack,  // (n, 8) packed
    const float* __restrict__ poly,  // (4, 3)
    float* __restrict__ out,         // (batch, 3)
    int batch, int n)
{
    const int tid = threadIdx.x;
    const int qbase = blockIdx.x * (BLK * QPT) + tid;
    const int j0 = blockIdx.y * CHUNK;
    const int jn = min(CHUNK, n - j0);

    float ux[QPT], uy[QPT], uz[QPT], usq[QPT];
    float ax[QPT], ay[QPT], az[QPT];

#pragma unroll
    for (int k = 0; k < QPT; ++k) {
        const int q = qbase + k * BLK;
        const int ql = q < batch ? q : batch - 1;  // safe load index
        ux[k] = u[ql * 3 + 0];
        uy[k] = u[ql * 3 + 1];
        uz[k] = u[ql * 3 + 2];
        usq[k] = fmaf(ux[k], ux[k], fmaf(uy[k], uy[k], uz[k] * uz[k]));
        ax[k] = ay[k] = az[k] = 0.f;
    }

    if (blockIdx.y == 0) {
#pragma unroll
        for (int k = 0; k < QPT; ++k) {
            ax[k] = poly[0] + ux[k] * poly[3] + uy[k] * poly[6] + uz[k] * poly[9];
            ay[k] = poly[1] + ux[k] * poly[4] + uy[k] * poly[7] + uz[k] * poly[10];
            az[k] = poly[2] + ux[k] * poly[5] + uy[k] * poly[8] + uz[k] * poly[11];
        }
    }

    const float* __restrict__ pj = pack + (size_t)j0 * 8;
#pragma unroll 4
    for (int j = 0; j < jn; ++j) {
        // Loop-uniform address -> scalar (s_load_dwordx8) on the SMEM pipe.
        const float m2x = pj[j * 8 + 0];
        const float m2y = pj[j * 8 + 1];
        const float m2z = pj[j * 8 + 2];
        const float c2  = pj[j * 8 + 3];
        const float wx  = pj[j * 8 + 4];
        const float wy  = pj[j * 8 + 5];
        const float wz  = pj[j * 8 + 6];
#pragma unroll
        for (int k = 0; k < QPT; ++k) {
            float r2 = fmaf(m2x, ux[k],
                       fmaf(m2y, uy[k],
                       fmaf(m2z, uz[k], c2 + usq[k])));
            r2 = fmaxf(r2, 1e-30f);
            const float kk = __builtin_amdgcn_sqrtf(r2) *
                             __builtin_amdgcn_logf(r2);
            ax[k] = fmaf(kk, wx, ax[k]);
            ay[k] = fmaf(kk, wy, ay[k]);
            az[k] = fmaf(kk, wz, az[k]);
        }
    }

#pragma unroll
    for (int k = 0; k < QPT; ++k) {
        const int q = qbase + k * BLK;
        if (q < batch) {
            atomicAdd(&out[q * 3 + 0], ax[k]);
            atomicAdd(&out[q * 3 + 1], ay[k]);
            atomicAdd(&out[q * 3 + 2], az[k]);
        }
    }
}

extern "C" void kernel_launch(void* const* d_in, const int* in_sizes, int n_in,
                              void* d_out, int out_size, void* d_ws, size_t ws_size,
                              hipStream_t stream) {
    const float* u    = (const float*)d_in[0];  // (batch,3)
    const float* cp   = (const float*)d_in[1];  // (n,3)
    const float* w    = (const float*)d_in[2];  // (n,3)
    const float* poly = (const float*)d_in[3];  // (4,3)
    float* out = (float*)d_out;
    float* pack = (float*)d_ws;                 // n * 8 floats (128 KB)

    const int batch = in_sizes[0] / 3;
    const int n     = in_sizes[1] / 3;

    // Pre-pack {-2c, |c|^2, C*w} per control point (d_ws is re-poisoned
    // before every call, so this must run every call -- it does).
    pack_kernel<<<(n + BLK - 1) / BLK, BLK, 0, stream>>>(cp, w, (float4*)pack, n);

    // Zero output for atomic accumulation (d_out poisoned to 0xAA).
    hipMemsetAsync(d_out, 0, (size_t)out_size * sizeof(float), stream);

    dim3 block(BLK);
    dim3 grid((batch + BLK * QPT - 1) / (BLK * QPT), (n + CHUNK - 1) / CHUNK);
    tps_kernel<<<grid, block, 0, stream>>>(u, pack, poly, out, batch, n);
}

// Round 4
// 89.138 us; speedup vs baseline: 1.4876x; 1.4876x over previous
//
#include <hip/hip_runtime.h>

// ThinPlateSpline: out = K_query @ rbf_weights + P_query @ poly_coeffs
//   K_ij = r*ln(r), r = ||u_i - c_j|| (d=3)
//   r*ln(r)*w = sqrt(r2) * log2(r2) * (0.5*ln2*w); C folded into packed w.
//
// R4: R3 was atomic-write bound (75 MB HBM writes, 1 TB/s ceiling). Fix:
// full in-block reduction -> zero atomics, one coalesced 192-float store
// per block. Block = 1024 thr (16 waves) = 64 queries x 16-way n-split;
// grid 256 blocks = 1/CU, 4 waves/SIMD. j-data is wave-uniform -> scalar
// s_load_dwordx8 from packed {-2c, |c|^2, C*w}; r2 via expanded-form fma
// chain (4 full-rate VALU). LDS partials [16][64*3] (stride 3 coprime with
// 32 banks -> conflict-free).

#define BLK 1024
#define QPB 64      // queries per block (= lanes per wave)
#define NSPLIT 16   // waves per block = n-splits

__global__ void pack_kernel(const float* __restrict__ cp,
                            const float* __restrict__ w,
                            float4* __restrict__ pack, int n) {
    const int j = blockIdx.x * blockDim.x + threadIdx.x;
    if (j >= n) return;
    const float C = 0.34657359027997264f;  // 0.5 * ln(2)
    const float cx = cp[j * 3 + 0], cy = cp[j * 3 + 1], cz = cp[j * 3 + 2];
    pack[j * 2 + 0] = make_float4(-2.f * cx, -2.f * cy, -2.f * cz,
                                  cx * cx + cy * cy + cz * cz);
    pack[j * 2 + 1] = make_float4(C * w[j * 3 + 0], C * w[j * 3 + 1],
                                  C * w[j * 3 + 2], 0.f);
}

__global__ __launch_bounds__(BLK) void tps_kernel(
    const float* __restrict__ u,     // (batch, 3)
    const float* __restrict__ pack,  // (n, 8) packed
    const float* __restrict__ poly,  // (4, 3)
    float* __restrict__ out,         // (batch, 3)
    int batch, int n)
{
    __shared__ float s_red[NSPLIT][QPB * 3];

    const int tid  = threadIdx.x;
    const int lane = tid & 63;
    // Force wave id into an SGPR so the j-loop addresses are provably
    // wave-uniform -> s_load on the scalar pipe.
    const int wid  = __builtin_amdgcn_readfirstlane(tid >> 6);

    const int q  = blockIdx.x * QPB + lane;
    const int ql = q < batch ? q : batch - 1;
    const float ux = u[ql * 3 + 0];
    const float uy = u[ql * 3 + 1];
    const float uz = u[ql * 3 + 2];
    const float usq = fmaf(ux, ux, fmaf(uy, uy, uz * uz));

    float ax = 0.f, ay = 0.f, az = 0.f;
    if (wid == 0) {  // polynomial term, added once per query
        ax = poly[0] + ux * poly[3] + uy * poly[6] + uz * poly[9];
        ay = poly[1] + ux * poly[4] + uy * poly[7] + uz * poly[10];
        az = poly[2] + ux * poly[5] + uy * poly[8] + uz * poly[11];
    }

    const int J0  = (n + NSPLIT - 1) / NSPLIT;
    const int jlo = wid * J0;
    const int jcnt = min(jlo + J0, n) - jlo;
    const float* __restrict__ pj = pack + (size_t)jlo * 8;

#pragma unroll 4
    for (int j = 0; j < jcnt; ++j) {
        const float m2x = pj[j * 8 + 0];
        const float m2y = pj[j * 8 + 1];
        const float m2z = pj[j * 8 + 2];
        const float c2  = pj[j * 8 + 3];
        const float wx  = pj[j * 8 + 4];
        const float wy  = pj[j * 8 + 5];
        const float wz  = pj[j * 8 + 6];

        float r2 = fmaf(m2x, ux, fmaf(m2y, uy, fmaf(m2z, uz, c2 + usq)));
        r2 = fmaxf(r2, 1e-30f);
        const float kk = __builtin_amdgcn_sqrtf(r2) * __builtin_amdgcn_logf(r2);
        ax = fmaf(kk, wx, ax);
        ay = fmaf(kk, wy, ay);
        az = fmaf(kk, wz, az);
    }

    s_red[wid][lane * 3 + 0] = ax;
    s_red[wid][lane * 3 + 1] = ay;
    s_red[wid][lane * 3 + 2] = az;
    __syncthreads();

    if (tid < QPB * 3) {
        float s = 0.f;
#pragma unroll
        for (int w2 = 0; w2 < NSPLIT; ++w2) s += s_red[w2][tid];
        const int qq = blockIdx.x * QPB + tid / 3;
        if (qq < batch) out[(size_t)blockIdx.x * (QPB * 3) + tid] = s;
    }
}

extern "C" void kernel_launch(void* const* d_in, const int* in_sizes, int n_in,
                              void* d_out, int out_size, void* d_ws, size_t ws_size,
                              hipStream_t stream) {
    const float* u    = (const float*)d_in[0];  // (batch,3)
    const float* cp   = (const float*)d_in[1];  // (n,3)
    const float* w    = (const float*)d_in[2];  // (n,3)
    const float* poly = (const float*)d_in[3];  // (4,3)
    float* out  = (float*)d_out;
    float* pack = (float*)d_ws;                 // n * 8 floats (128 KB)

    const int batch = in_sizes[0] / 3;
    const int n     = in_sizes[1] / 3;

    pack_kernel<<<(n + 255) / 256, 256, 0, stream>>>(cp, w, (float4*)pack, n);

    dim3 block(BLK);
    dim3 grid((batch + QPB - 1) / QPB);
    tps_kernel<<<grid, block, 0, stream>>>(u, pack, poly, out, batch, n);
}

// Round 5
// 87.668 us; speedup vs baseline: 1.5125x; 1.0168x over previous
//
#include <hip/hip_runtime.h>

// ThinPlateSpline: out = K_query @ rbf_weights + P_query @ poly_coeffs
//   K_ij = r*ln(r), r = ||u_i - c_j|| (d=3)
//   r*ln(r)*w = sqrt(r2)*log2(r2) * (0.5*ln2*w); C folded into staged w.
//   r2 = usq + |c|^2 - 2 u.c  (expanded form, 4 full-rate VALU ops)
//
// R5: R4's uniform j-loop loads were NOT scalarized -> ~7 vector global
// loads/j dominated issue. Deliver j-data via LDS broadcast (2x
// ds_read_b128 per j), amortized over QPT=2 queries/lane. Block = 512 thr
// = 2 query-groups x 4 n-splits; grid (64,8) = 512 blocks -> 4 waves/SIMD.
// Staging transform done in-kernel (pack kernel deleted). Atomics only
// across grid.y=8 n-chunks: 393K atomics ~ 5 MB HBM, overlapped.

#define BLK 512
#define QPB 256     // queries per block = 2 groups * (QPT=2) * 64 lanes
#define NS 4        // in-block n-splits (waves 2w..2w+1 share a split)
#define JCHUNK 512  // j's per block = n / gridDim.y
#define JW (JCHUNK / NS)

__global__ __launch_bounds__(BLK) void tps_kernel(
    const float* __restrict__ u,     // (batch, 3)
    const float* __restrict__ cp,    // (n, 3)
    const float* __restrict__ w,     // (n, 3)
    const float* __restrict__ poly,  // (4, 3)
    float* __restrict__ out,         // (batch, 3)
    int batch, int n)
{
    __shared__ float4 s_a[JCHUNK];  // {-2cx, -2cy, -2cz, |c|^2}
    __shared__ float4 s_b[JCHUNK];  // {C*wx, C*wy, C*wz, 0}

    const float C = 0.34657359027997264f;  // 0.5 * ln(2)

    const int tid = threadIdx.x;
    const int j0 = blockIdx.y * JCHUNK;

    // Stage + transform this block's j-slice (512 j -> 16 KB, one pass).
    {
        const int t = tid;  // BLK == JCHUNK
        const int g = j0 + t;
        const float cx = cp[g * 3 + 0], cy = cp[g * 3 + 1], cz = cp[g * 3 + 2];
        s_a[t] = make_float4(-2.f * cx, -2.f * cy, -2.f * cz,
                             fmaf(cx, cx, fmaf(cy, cy, cz * cz)));
        s_b[t] = make_float4(C * w[g * 3 + 0], C * w[g * 3 + 1],
                             C * w[g * 3 + 2], 0.f);
    }
    __syncthreads();

    const int lane = tid & 63;
    const int wave = tid >> 6;   // 0..7
    const int qg   = wave & 1;   // query group
    const int ns   = wave >> 1;  // n-split 0..3

    const int q0 = blockIdx.x * QPB + qg * 128 + lane;
    const int q1 = q0 + 64;

    const float ux0 = u[q0 * 3 + 0], uy0 = u[q0 * 3 + 1], uz0 = u[q0 * 3 + 2];
    const float ux1 = u[q1 * 3 + 0], uy1 = u[q1 * 3 + 1], uz1 = u[q1 * 3 + 2];
    const float usq0 = fmaf(ux0, ux0, fmaf(uy0, uy0, uz0 * uz0));
    const float usq1 = fmaf(ux1, ux1, fmaf(uy1, uy1, uz1 * uz1));

    float ax0 = 0.f, ay0 = 0.f, az0 = 0.f;
    float ax1 = 0.f, ay1 = 0.f, az1 = 0.f;
    if (blockIdx.y == 0 && ns == 0) {  // poly term added exactly once
        ax0 = poly[0] + ux0 * poly[3] + uy0 * poly[6] + uz0 * poly[9];
        ay0 = poly[1] + ux0 * poly[4] + uy0 * poly[7] + uz0 * poly[10];
        az0 = poly[2] + ux0 * poly[5] + uy0 * poly[8] + uz0 * poly[11];
        ax1 = poly[0] + ux1 * poly[3] + uy1 * poly[6] + uz1 * poly[9];
        ay1 = poly[1] + ux1 * poly[4] + uy1 * poly[7] + uz1 * poly[10];
        az1 = poly[2] + ux1 * poly[5] + uy1 * poly[8] + uz1 * poly[11];
    }

    const int jlo = ns * JW;
#pragma unroll 4
    for (int j = jlo; j < jlo + JW; ++j) {
        const float4 A = s_a[j];  // broadcast: all lanes same address
        const float4 B = s_b[j];

        float r20 = fmaf(A.x, ux0, fmaf(A.y, uy0, fmaf(A.z, uz0, A.w + usq0)));
        r20 = fmaxf(r20, 1e-30f);
        const float k0 = __builtin_amdgcn_sqrtf(r20) * __builtin_amdgcn_logf(r20);
        ax0 = fmaf(k0, B.x, ax0);
        ay0 = fmaf(k0, B.y, ay0);
        az0 = fmaf(k0, B.z, az0);

        float r21 = fmaf(A.x, ux1, fmaf(A.y, uy1, fmaf(A.z, uz1, A.w + usq1)));
        r21 = fmaxf(r21, 1e-30f);
        const float k1 = __builtin_amdgcn_sqrtf(r21) * __builtin_amdgcn_logf(r21);
        ax1 = fmaf(k1, B.x, ax1);
        ay1 = fmaf(k1, B.y, ay1);
        az1 = fmaf(k1, B.z, az1);
    }

    atomicAdd(&out[q0 * 3 + 0], ax0);
    atomicAdd(&out[q0 * 3 + 1], ay0);
    atomicAdd(&out[q0 * 3 + 2], az0);
    atomicAdd(&out[q1 * 3 + 0], ax1);
    atomicAdd(&out[q1 * 3 + 1], ay1);
    atomicAdd(&out[q1 * 3 + 2], az1);
}

extern "C" void kernel_launch(void* const* d_in, const int* in_sizes, int n_in,
                              void* d_out, int out_size, void* d_ws, size_t ws_size,
                              hipStream_t stream) {
    const float* u    = (const float*)d_in[0];  // (batch,3)
    const float* cp   = (const float*)d_in[1];  // (n,3)
    const float* w    = (const float*)d_in[2];  // (n,3)
    const float* poly = (const float*)d_in[3];  // (4,3)
    float* out = (float*)d_out;

    const int batch = in_sizes[0] / 3;  // 16384
    const int n     = in_sizes[1] / 3;  // 4096

    // Zero output for atomic accumulation (d_out poisoned to 0xAA).
    hipMemsetAsync(d_out, 0, (size_t)out_size * sizeof(float), stream);

    dim3 block(BLK);
    dim3 grid(batch / QPB, n / JCHUNK);  // (64, 8) for 16384 x 4096
    tps_kernel<<<grid, block, 0, stream>>>(u, cp, w, poly, out, batch, n);
}